// Round 7
// baseline (364.550 us; speedup 1.0000x reference)
//
#include <hip/hip_runtime.h>
#include <hip/hip_fp16.h>

using f32x4  = __attribute__((ext_vector_type(4))) float;
using short8 = __attribute__((ext_vector_type(8))) short;
using ushort4_t = __attribute__((ext_vector_type(4))) unsigned short;

#define XP 136  // padded LDS pitch in bf16 elems
#define LOG2E 1.4426950408889634f

static __device__ __forceinline__ unsigned short f2bf(float f) {
  union { float f; unsigned u; } c; c.f = f;
  unsigned u = c.u;
  return (unsigned short)((u + 0x7fffu + ((u >> 16) & 1u)) >> 16);  // RNE
}
static __device__ __forceinline__ float bf2f(unsigned short b) {
  union { unsigned u; float f; } c; c.u = ((unsigned)b) << 16;
  return c.f;
}
static __device__ __forceinline__ float h2f_bits(unsigned short b) {
  __half_raw r; r.x = b;
  return __half2float(__half(r));
}

// edge_index may arrive as int64 (reference dtype) or int32 (harness downcast).
__global__ __launch_bounds__(64) void k_detect(const void* ei, int nnodes, int* flag) {
  const long long* e64 = (const long long*)ei;
  long long v = e64[threadIdx.x];
  int ok = (v >= 0 && v < (long long)nnodes) ? 1 : 0;
  unsigned long long m = __ballot(ok);
  if (threadIdx.x == 0) *flag = (m == ~0ull) ? 1 : 0;
}

// K1: h = x @ W (bf16 MFMA, f32 accum), h stored bf16.
// Epilogue computes ssrc/sdst[n][4] (PRE-SCALED by log2e) via butterfly reduce.
__global__ __launch_bounds__(256) void k_gemm(const float* __restrict__ x,
                                              const float* __restrict__ W,
                                              const float* __restrict__ a,
                                              unsigned short* __restrict__ hbf,
                                              float* __restrict__ ssrc,
                                              float* __restrict__ sdst, int nnodes) {
  __shared__ __align__(16) unsigned short lx[64 * XP];
  __shared__ __align__(16) unsigned short lw[128 * XP];
  const int tid = threadIdx.x;
  const int n0 = blockIdx.x * 64;

  for (int it = 0; it < 8; ++it) {
    int idx = tid + it * 256;
    int r = idx >> 5, i4 = idx & 31;
    int n = n0 + r;
    float4 v = make_float4(0.f, 0.f, 0.f, 0.f);
    if (n < nnodes) v = *(const float4*)(x + (size_t)n * 128 + i4 * 4);
    ushort4_t b; b.x = f2bf(v.x); b.y = f2bf(v.y); b.z = f2bf(v.z); b.w = f2bf(v.w);
    *(ushort4_t*)&lx[r * XP + i4 * 4] = b;
  }
  for (int it = 0; it < 64; ++it) {
    int idx = tid + it * 256;
    int hh = idx >> 12, i = (idx >> 5) & 127, o = idx & 31;
    int col = hh * 32 + o;
    lw[col * XP + i] = f2bf(W[idx]);
  }
  __syncthreads();

  const int wave = tid >> 6, lane = tid & 63;
  const int m0 = wave * 16;
  const int lr = lane & 15, lh = lane >> 4;

  f32x4 acc[8] = {};
  for (int kk = 0; kk < 4; ++kk) {
    short8 av = *(const short8*)&lx[(m0 + lr) * XP + kk * 32 + lh * 8];
#pragma unroll
    for (int f = 0; f < 8; ++f) {
      short8 bv = *(const short8*)&lw[(f * 16 + lr) * XP + kk * 32 + lh * 8];
      acc[f] = __builtin_amdgcn_mfma_f32_16x16x32_bf16(av, bv, acc[f], 0, 0, 0);
    }
  }

  float avc[4][4];
#pragma unroll
  for (int hh = 0; hh < 4; ++hh) {
    avc[hh][0] = a[hh * 64 + lr];
    avc[hh][1] = a[hh * 64 + 16 + lr];
    avc[hh][2] = a[hh * 64 + 32 + lr];
    avc[hh][3] = a[hh * 64 + 48 + lr];
  }

#pragma unroll
  for (int j = 0; j < 4; ++j) {
    int n = n0 + m0 + lh * 4 + j;
#pragma unroll
    for (int f = 0; f < 8; ++f) {
      if (n < nnodes) hbf[(size_t)n * 128 + f * 16 + lr] = f2bf(acc[f][j]);
    }
#pragma unroll
    for (int hh = 0; hh < 4; ++hh) {
      float s0 = acc[2 * hh][j] * avc[hh][0] + acc[2 * hh + 1][j] * avc[hh][1];
      float s1 = acc[2 * hh][j] * avc[hh][2] + acc[2 * hh + 1][j] * avc[hh][3];
#pragma unroll
      for (int m = 1; m < 16; m <<= 1) {
        s0 += __shfl_xor(s0, m);
        s1 += __shfl_xor(s1, m);
      }
      if (lr == hh && n < nnodes) {
        ssrc[(size_t)n * 4 + hh] = s0 * LOG2E;   // pre-scaled for exp2
        sdst[(size_t)n * 4 + hh] = s1 * LOG2E;
      }
    }
  }
}

// ---- CSR build ----
__global__ __launch_bounds__(256) void k_prep(const void* __restrict__ ei, const int* __restrict__ flag,
                                              int* __restrict__ src32, int* __restrict__ dst32,
                                              int* __restrict__ deg, int E) {
  int e = blockIdx.x * 256 + threadIdx.x;
  if (e >= E) return;
  int is64 = *flag;
  int s, d;
  if (is64) {
    s = (int)__builtin_nontemporal_load(((const long long*)ei) + e);
    d = (int)__builtin_nontemporal_load(((const long long*)ei) + E + e);
  } else {
    s = __builtin_nontemporal_load(((const int*)ei) + e);
    d = __builtin_nontemporal_load(((const int*)ei) + E + e);
  }
  src32[e] = s;
  dst32[e] = d;
  atomicAdd(&deg[d], 1);
}

__global__ __launch_bounds__(256) void k_scan1(const int* __restrict__ deg, int* __restrict__ rowstart,
                                               int* __restrict__ bsum, int N) {
  __shared__ int l[256];
  int t = threadIdx.x;
  int gid = blockIdx.x * 256 + t;
  int v = (gid < N) ? deg[gid] : 0;
  l[t] = v;
  __syncthreads();
  for (int off = 1; off < 256; off <<= 1) {
    int u = (t >= off) ? l[t - off] : 0;
    __syncthreads();
    l[t] += u;
    __syncthreads();
  }
  if (gid < N) rowstart[gid] = l[t] - v;
  if (t == 255) bsum[blockIdx.x] = l[255];
}

__global__ __launch_bounds__(512) void k_scan2(int* __restrict__ bsum, int nb) {
  __shared__ int l[512];
  int t = threadIdx.x;
  int v = (t < nb) ? bsum[t] : 0;
  l[t] = v;
  __syncthreads();
  for (int off = 1; off < 512; off <<= 1) {
    int u = (t >= off) ? l[t - off] : 0;
    __syncthreads();
    l[t] += u;
    __syncthreads();
  }
  if (t < nb) bsum[t] = l[t] - v;
}

__global__ __launch_bounds__(256) void k_scan3(int* __restrict__ rowstart, const int* __restrict__ bsum,
                                               int* __restrict__ cursor, int N) {
  int gid = blockIdx.x * 256 + threadIdx.x;
  if (gid < N) {
    int r = rowstart[gid] + bsum[blockIdx.x];
    rowstart[gid] = r;
    cursor[gid] = r;
  }
}

// Partitioned scatter + per-edge softmax numerators.
// Partition p = blockIdx%8 handles dst range [p*N/8,(p+1)*N/8): each XCD-L2's hot
// write window (eidx 0.8MB + ph 1.6MB) stays resident. Streaming src32/dst32
// reads are NON-TEMPORAL so they don't evict partially-filled write lines
// (R5's 8x write amplification came from exactly that eviction).
__global__ __launch_bounds__(256) void k_scatter(const int* __restrict__ src32,
                                                 const int* __restrict__ dst32,
                                                 const float* __restrict__ ssrc,
                                                 const float* __restrict__ sdst,
                                                 int* __restrict__ cursor,
                                                 int* __restrict__ eidx,
                                                 unsigned short* __restrict__ ph,
                                                 int E, int N) {
  const int part = blockIdx.x & 7;
  const int wblk = blockIdx.x >> 3;
  const int nwb = gridDim.x >> 3;
  const int lo = (int)(((long long)N * part) >> 3);
  const int hi = (int)(((long long)N * (part + 1)) >> 3);
  for (int e = wblk * 256 + threadIdx.x; e < E; e += nwb * 256) {
    int d = __builtin_nontemporal_load(dst32 + e);
    if (d >= lo && d < hi) {
      int s = __builtin_nontemporal_load(src32 + e);
      int pos = atomicAdd(&cursor[d], 1);
      eidx[pos] = s;
      float4 ss = *(const float4*)(ssrc + (size_t)s * 4);
      float4 sd = *(const float4*)(sdst + (size_t)d * 4);
      float e0 = ss.x + sd.x, e1 = ss.y + sd.y, e2 = ss.z + sd.z, e3 = ss.w + sd.w;
      e0 = fmaxf(e0, 0.2f * e0);  // leaky (valid both signs)
      e1 = fmaxf(e1, 0.2f * e1);
      e2 = fmaxf(e2, 0.2f * e2);
      e3 = fmaxf(e3, 0.2f * e3);
      float p0 = exp2f(e0), p1 = exp2f(e1), p2 = exp2f(e2), p3 = exp2f(e3);
      __half2 lo2 = __floats2half2_rn(p0, p1);
      __half2 hi2 = __floats2half2_rn(p2, p3);
      uint2 pk = make_uint2(*(unsigned*)&lo2, *(unsigned*)&hi2);
      *(uint2*)(ph + (size_t)pos * 4) = pk;
    }
  }
}

// ---- gather: one wave per dst; bf16 h; p precomputed; nt on streams so h keeps L2 ----
__global__ __launch_bounds__(256) void k_gather(const unsigned short* __restrict__ hbf,
                                                const int* __restrict__ rowstart,
                                                const int* __restrict__ deg,
                                                const int* __restrict__ eidx,
                                                const unsigned short* __restrict__ ph,
                                                float* __restrict__ out, int N) {
  int wid = (blockIdx.x * 256 + threadIdx.x) >> 6;
  int lane = threadIdx.x & 63;
  if (wid >= N) return;
  const int dst = wid;
  const int beg = rowstart[dst];
  const int end = beg + deg[dst];
  const unsigned hh = (unsigned)(lane >> 4);        // head of cols {2*lane,2*lane+1}
  const unsigned* __restrict__ h32 = (const unsigned*)hbf;
  float acc0 = 0.f, acc1 = 0.f, ps = 0.f;

  int i = beg;
  for (; i + 3 < end; i += 4) {
    int sA = __builtin_nontemporal_load(eidx + i);
    int sB = __builtin_nontemporal_load(eidx + i + 1);
    int sC = __builtin_nontemporal_load(eidx + i + 2);
    int sD = __builtin_nontemporal_load(eidx + i + 3);
    unsigned hvA = h32[((unsigned)sA << 6) | (unsigned)lane];
    unsigned hvB = h32[((unsigned)sB << 6) | (unsigned)lane];
    unsigned hvC = h32[((unsigned)sC << 6) | (unsigned)lane];
    unsigned hvD = h32[((unsigned)sD << 6) | (unsigned)lane];
    unsigned short ra = __builtin_nontemporal_load(ph + (((unsigned)i) << 2) + hh);
    unsigned short rb = __builtin_nontemporal_load(ph + (((unsigned)i + 1u) << 2) + hh);
    unsigned short rc = __builtin_nontemporal_load(ph + (((unsigned)i + 2u) << 2) + hh);
    unsigned short rd = __builtin_nontemporal_load(ph + (((unsigned)i + 3u) << 2) + hh);
    float pA = h2f_bits(ra), pB = h2f_bits(rb);
    float pC = h2f_bits(rc), pD = h2f_bits(rd);
    acc0 += pA * bf2f((unsigned short)(hvA & 0xffff));
    acc1 += pA * bf2f((unsigned short)(hvA >> 16));
    acc0 += pB * bf2f((unsigned short)(hvB & 0xffff));
    acc1 += pB * bf2f((unsigned short)(hvB >> 16));
    acc0 += pC * bf2f((unsigned short)(hvC & 0xffff));
    acc1 += pC * bf2f((unsigned short)(hvC >> 16));
    acc0 += pD * bf2f((unsigned short)(hvD & 0xffff));
    acc1 += pD * bf2f((unsigned short)(hvD >> 16));
    ps += (pA + pB) + (pC + pD);
  }
  for (; i < end; ++i) {
    int sA = __builtin_nontemporal_load(eidx + i);
    unsigned hvA = h32[((unsigned)sA << 6) | (unsigned)lane];
    float pA = h2f_bits(__builtin_nontemporal_load(ph + (((unsigned)i) << 2) + hh));
    acc0 += pA * bf2f((unsigned short)(hvA & 0xffff));
    acc1 += pA * bf2f((unsigned short)(hvA >> 16));
    ps += pA;
  }
  float r = (ps > 0.f) ? 1.f / ps : 0.f;
  __builtin_nontemporal_store(acc0 * r, out + (size_t)dst * 128 + lane * 2);
  __builtin_nontemporal_store(acc1 * r, out + (size_t)dst * 128 + lane * 2 + 1);
}

extern "C" void kernel_launch(void* const* d_in, const int* in_sizes, int n_in,
                              void* d_out, int out_size, void* d_ws, size_t ws_size,
                              hipStream_t stream) {
  const float* x = (const float*)d_in[0];
  const void*  ei = d_in[1];
  const float* W = (const float*)d_in[2];
  const float* a = (const float*)d_in[3];
  float* out = (float*)d_out;

  const int N = in_sizes[0] / 128;
  const int E = in_sizes[1] / 2;
  const int NB = (N + 255) / 256;              // scan blocks (<=512)

  char* ws = (char*)d_ws;
  unsigned short* hbf = (unsigned short*)ws;             ws += (size_t)N * 128 * 2;
  float* ssrc     = (float*)ws;                          ws += (size_t)N * 4 * 4;
  float* sdst     = (float*)ws;                          ws += (size_t)N * 4 * 4;
  int*   deg      = (int*)ws;                            ws += (size_t)N * 4;
  int*   rowstart = (int*)ws;                            ws += (size_t)N * 4;
  int*   cursor   = (int*)ws;                            ws += (size_t)N * 4;
  int*   bsum     = (int*)ws;                            ws += 512 * 4;
  int*   eidx     = (int*)ws;                            ws += (size_t)E * 4;
  unsigned short* ph = (unsigned short*)ws;              ws += (size_t)E * 4 * 2;
  int*   flag     = (int*)ws;

  // src32/dst32 scratch aliased into d_out (12.8 MB << 51.2 MB); dead before
  // k_gather overwrites all of d_out.
  int* src32 = (int*)d_out;
  int* dst32 = src32 + E;

  hipMemsetAsync(deg, 0, (size_t)N * 4, stream);

  k_detect<<<1, 64, 0, stream>>>(ei, N, flag);
  k_gemm<<<(N + 63) / 64, 256, 0, stream>>>(x, W, a, hbf, ssrc, sdst, N);
  k_prep<<<(E + 255) / 256, 256, 0, stream>>>(ei, flag, src32, dst32, deg, E);
  k_scan1<<<NB, 256, 0, stream>>>(deg, rowstart, bsum, N);
  k_scan2<<<1, 512, 0, stream>>>(bsum, NB);
  k_scan3<<<NB, 256, 0, stream>>>(rowstart, bsum, cursor, N);
  k_scatter<<<2048, 256, 0, stream>>>(src32, dst32, ssrc, sdst, cursor, eidx, ph, E, N);
  k_gather<<<(N + 3) / 4, 256, 0, stream>>>(hbf, rowstart, deg, eidx, ph, out, N);
}

// Round 8
// 300.484 us; speedup vs baseline: 1.2132x; 1.2132x over previous
//
#include <hip/hip_runtime.h>
#include <hip/hip_fp16.h>

using f32x4  = __attribute__((ext_vector_type(4))) float;
using short8 = __attribute__((ext_vector_type(8))) short;
using ushort4_t = __attribute__((ext_vector_type(4))) unsigned short;

#define XP 136  // padded LDS pitch in bf16 elems
#define LOG2E 1.4426950408889634f

static __device__ __forceinline__ unsigned short f2bf(float f) {
  union { float f; unsigned u; } c; c.f = f;
  unsigned u = c.u;
  return (unsigned short)((u + 0x7fffu + ((u >> 16) & 1u)) >> 16);  // RNE
}
static __device__ __forceinline__ float bf2f(unsigned short b) {
  union { unsigned u; float f; } c; c.u = ((unsigned)b) << 16;
  return c.f;
}
static __device__ __forceinline__ float h2f_bits(unsigned short b) {
  __half_raw r; r.x = b;
  return __half2float(__half(r));
}

// edge_index may arrive as int64 (reference dtype) or int32 (harness downcast).
__global__ __launch_bounds__(64) void k_detect(const void* ei, int nnodes, int* flag) {
  const long long* e64 = (const long long*)ei;
  long long v = e64[threadIdx.x];
  int ok = (v >= 0 && v < (long long)nnodes) ? 1 : 0;
  unsigned long long m = __ballot(ok);
  if (threadIdx.x == 0) *flag = (m == ~0ull) ? 1 : 0;
}

// K1: h = x @ W (bf16 MFMA, f32 accum), h stored bf16.
// Epilogue computes ssrc/sdst[n][4] (PRE-SCALED by log2e) via butterfly reduce.
__global__ __launch_bounds__(256) void k_gemm(const float* __restrict__ x,
                                              const float* __restrict__ W,
                                              const float* __restrict__ a,
                                              unsigned short* __restrict__ hbf,
                                              float* __restrict__ ssrc,
                                              float* __restrict__ sdst, int nnodes) {
  __shared__ __align__(16) unsigned short lx[64 * XP];
  __shared__ __align__(16) unsigned short lw[128 * XP];
  const int tid = threadIdx.x;
  const int n0 = blockIdx.x * 64;

  for (int it = 0; it < 8; ++it) {
    int idx = tid + it * 256;
    int r = idx >> 5, i4 = idx & 31;
    int n = n0 + r;
    float4 v = make_float4(0.f, 0.f, 0.f, 0.f);
    if (n < nnodes) v = *(const float4*)(x + (size_t)n * 128 + i4 * 4);
    ushort4_t b; b.x = f2bf(v.x); b.y = f2bf(v.y); b.z = f2bf(v.z); b.w = f2bf(v.w);
    *(ushort4_t*)&lx[r * XP + i4 * 4] = b;
  }
  for (int it = 0; it < 64; ++it) {
    int idx = tid + it * 256;
    int hh = idx >> 12, i = (idx >> 5) & 127, o = idx & 31;
    int col = hh * 32 + o;
    lw[col * XP + i] = f2bf(W[idx]);
  }
  __syncthreads();

  const int wave = tid >> 6, lane = tid & 63;
  const int m0 = wave * 16;
  const int lr = lane & 15, lh = lane >> 4;

  f32x4 acc[8] = {};
  for (int kk = 0; kk < 4; ++kk) {
    short8 av = *(const short8*)&lx[(m0 + lr) * XP + kk * 32 + lh * 8];
#pragma unroll
    for (int f = 0; f < 8; ++f) {
      short8 bv = *(const short8*)&lw[(f * 16 + lr) * XP + kk * 32 + lh * 8];
      acc[f] = __builtin_amdgcn_mfma_f32_16x16x32_bf16(av, bv, acc[f], 0, 0, 0);
    }
  }

  float avc[4][4];
#pragma unroll
  for (int hh = 0; hh < 4; ++hh) {
    avc[hh][0] = a[hh * 64 + lr];
    avc[hh][1] = a[hh * 64 + 16 + lr];
    avc[hh][2] = a[hh * 64 + 32 + lr];
    avc[hh][3] = a[hh * 64 + 48 + lr];
  }

#pragma unroll
  for (int j = 0; j < 4; ++j) {
    int n = n0 + m0 + lh * 4 + j;
#pragma unroll
    for (int f = 0; f < 8; ++f) {
      if (n < nnodes) hbf[(size_t)n * 128 + f * 16 + lr] = f2bf(acc[f][j]);
    }
#pragma unroll
    for (int hh = 0; hh < 4; ++hh) {
      float s0 = acc[2 * hh][j] * avc[hh][0] + acc[2 * hh + 1][j] * avc[hh][1];
      float s1 = acc[2 * hh][j] * avc[hh][2] + acc[2 * hh + 1][j] * avc[hh][3];
#pragma unroll
      for (int m = 1; m < 16; m <<= 1) {
        s0 += __shfl_xor(s0, m);
        s1 += __shfl_xor(s1, m);
      }
      if (lr == hh && n < nnodes) {
        ssrc[(size_t)n * 4 + hh] = s0 * LOG2E;   // pre-scaled for exp2
        sdst[(size_t)n * 4 + hh] = s1 * LOG2E;
      }
    }
  }
}

// ---- CSR build ----
__global__ __launch_bounds__(256) void k_prep(const void* __restrict__ ei, const int* __restrict__ flag,
                                              int* __restrict__ src32, int* __restrict__ dst32,
                                              int* __restrict__ deg, int E) {
  int e = blockIdx.x * 256 + threadIdx.x;
  if (e >= E) return;
  int is64 = *flag;
  int s, d;
  if (is64) {
    s = (int)((const long long*)ei)[e];
    d = (int)((const long long*)ei)[(size_t)E + e];
  } else {
    s = ((const int*)ei)[e];
    d = ((const int*)ei)[(size_t)E + e];
  }
  src32[e] = s;
  dst32[e] = d;
  atomicAdd(&deg[d], 1);
}

__global__ __launch_bounds__(256) void k_scan1(const int* __restrict__ deg, int* __restrict__ rowstart,
                                               int* __restrict__ bsum, int N) {
  __shared__ int l[256];
  int t = threadIdx.x;
  int gid = blockIdx.x * 256 + t;
  int v = (gid < N) ? deg[gid] : 0;
  l[t] = v;
  __syncthreads();
  for (int off = 1; off < 256; off <<= 1) {
    int u = (t >= off) ? l[t - off] : 0;
    __syncthreads();
    l[t] += u;
    __syncthreads();
  }
  if (gid < N) rowstart[gid] = l[t] - v;
  if (t == 255) bsum[blockIdx.x] = l[255];
}

__global__ __launch_bounds__(512) void k_scan2(int* __restrict__ bsum, int nb) {
  __shared__ int l[512];
  int t = threadIdx.x;
  int v = (t < nb) ? bsum[t] : 0;
  l[t] = v;
  __syncthreads();
  for (int off = 1; off < 512; off <<= 1) {
    int u = (t >= off) ? l[t - off] : 0;
    __syncthreads();
    l[t] += u;
    __syncthreads();
  }
  if (t < nb) bsum[t] = l[t] - v;
}

__global__ __launch_bounds__(256) void k_scan3(int* __restrict__ rowstart, const int* __restrict__ bsum,
                                               int* __restrict__ cursor, int N) {
  int gid = blockIdx.x * 256 + threadIdx.x;
  if (gid < N) {
    int r = rowstart[gid] + bsum[blockIdx.x];
    rowstart[gid] = r;
    cursor[gid] = r;
  }
}

// Partitioned scatter, eidx ONLY (R4-proven: 0.8MB/XCD write window -> no
// write amplification). All softmax work moved to k_attn (sequential writes).
__global__ __launch_bounds__(256) void k_scatter(const int* __restrict__ src32,
                                                 const int* __restrict__ dst32,
                                                 int* __restrict__ cursor,
                                                 int* __restrict__ eidx, int E, int N) {
  const int part = blockIdx.x & 7;
  const int wblk = blockIdx.x >> 3;
  const int nwb = gridDim.x >> 3;
  const int lo = (int)(((long long)N * part) >> 3);
  const int hi = (int)(((long long)N * (part + 1)) >> 3);
  for (int e = wblk * 256 + threadIdx.x; e < E; e += nwb * 256) {
    int d = dst32[e];
    if (d >= lo && d < hi) {
      int pos = atomicAdd(&cursor[d], 1);
      eidx[pos] = src32[e];
    }
  }
}

// Per-edge softmax numerators in SLOT order: thread per dst walks its row.
// eidx reads and ph writes are sequential (no write amplification possible);
// ssrc is a 1.6MB table -> L2-resident random reads.
__global__ __launch_bounds__(256) void k_attn(const int* __restrict__ rowstart,
                                              const int* __restrict__ deg,
                                              const int* __restrict__ eidx,
                                              const float* __restrict__ ssrc,
                                              const float* __restrict__ sdst,
                                              unsigned short* __restrict__ ph, int N) {
  int d = blockIdx.x * 256 + threadIdx.x;
  if (d >= N) return;
  const int beg = rowstart[d];
  const int cnt = deg[d];
  float4 sd = *(const float4*)(sdst + (size_t)d * 4);
  for (int k = 0; k < cnt; ++k) {
    int i = beg + k;
    int s = eidx[i];
    float4 ss = *(const float4*)(ssrc + (size_t)s * 4);
    float e0 = ss.x + sd.x, e1 = ss.y + sd.y, e2 = ss.z + sd.z, e3 = ss.w + sd.w;
    e0 = fmaxf(e0, 0.2f * e0);
    e1 = fmaxf(e1, 0.2f * e1);
    e2 = fmaxf(e2, 0.2f * e2);
    e3 = fmaxf(e3, 0.2f * e3);
    __half2 lo2 = __floats2half2_rn(exp2f(e0), exp2f(e1));
    __half2 hi2 = __floats2half2_rn(exp2f(e2), exp2f(e3));
    uint2 pk = make_uint2(*(unsigned*)&lo2, *(unsigned*)&hi2);
    *(uint2*)(ph + (size_t)i * 4) = pk;
  }
}

// ---- gather: one wave per dst; bf16 h; p precomputed ----
__global__ __launch_bounds__(256) void k_gather(const unsigned short* __restrict__ hbf,
                                                const int* __restrict__ rowstart,
                                                const int* __restrict__ deg,
                                                const int* __restrict__ eidx,
                                                const unsigned short* __restrict__ ph,
                                                float* __restrict__ out, int N) {
  int wid = (blockIdx.x * 256 + threadIdx.x) >> 6;
  int lane = threadIdx.x & 63;
  if (wid >= N) return;
  const int dst = wid;
  const int beg = rowstart[dst];
  const int end = beg + deg[dst];
  const unsigned hh = (unsigned)(lane >> 4);        // head of cols {2*lane,2*lane+1}
  const unsigned* __restrict__ h32 = (const unsigned*)hbf;
  float acc0 = 0.f, acc1 = 0.f, ps = 0.f;

  int i = beg;
  for (; i + 3 < end; i += 4) {
    int sA = eidx[i], sB = eidx[i + 1], sC = eidx[i + 2], sD = eidx[i + 3];
    unsigned hvA = h32[((unsigned)sA << 6) | (unsigned)lane];
    unsigned hvB = h32[((unsigned)sB << 6) | (unsigned)lane];
    unsigned hvC = h32[((unsigned)sC << 6) | (unsigned)lane];
    unsigned hvD = h32[((unsigned)sD << 6) | (unsigned)lane];
    float pA = h2f_bits(ph[(((unsigned)i) << 2) | hh]);
    float pB = h2f_bits(ph[(((unsigned)i + 1u) << 2) | hh]);
    float pC = h2f_bits(ph[(((unsigned)i + 2u) << 2) | hh]);
    float pD = h2f_bits(ph[(((unsigned)i + 3u) << 2) | hh]);
    acc0 += pA * bf2f((unsigned short)(hvA & 0xffff));
    acc1 += pA * bf2f((unsigned short)(hvA >> 16));
    acc0 += pB * bf2f((unsigned short)(hvB & 0xffff));
    acc1 += pB * bf2f((unsigned short)(hvB >> 16));
    acc0 += pC * bf2f((unsigned short)(hvC & 0xffff));
    acc1 += pC * bf2f((unsigned short)(hvC >> 16));
    acc0 += pD * bf2f((unsigned short)(hvD & 0xffff));
    acc1 += pD * bf2f((unsigned short)(hvD >> 16));
    ps += (pA + pB) + (pC + pD);
  }
  for (; i < end; ++i) {
    int sA = eidx[i];
    unsigned hvA = h32[((unsigned)sA << 6) | (unsigned)lane];
    float pA = h2f_bits(ph[(((unsigned)i) << 2) | hh]);
    acc0 += pA * bf2f((unsigned short)(hvA & 0xffff));
    acc1 += pA * bf2f((unsigned short)(hvA >> 16));
    ps += pA;
  }
  float r = (ps > 0.f) ? 1.f / ps : 0.f;
  __builtin_nontemporal_store(acc0 * r, out + (size_t)dst * 128 + lane * 2);
  __builtin_nontemporal_store(acc1 * r, out + (size_t)dst * 128 + lane * 2 + 1);
}

extern "C" void kernel_launch(void* const* d_in, const int* in_sizes, int n_in,
                              void* d_out, int out_size, void* d_ws, size_t ws_size,
                              hipStream_t stream) {
  const float* x = (const float*)d_in[0];
  const void*  ei = d_in[1];
  const float* W = (const float*)d_in[2];
  const float* a = (const float*)d_in[3];
  float* out = (float*)d_out;

  const int N = in_sizes[0] / 128;
  const int E = in_sizes[1] / 2;
  const int NB = (N + 255) / 256;              // scan blocks (<=512)

  char* ws = (char*)d_ws;
  unsigned short* hbf = (unsigned short*)ws;             ws += (size_t)N * 128 * 2;
  float* ssrc     = (float*)ws;                          ws += (size_t)N * 4 * 4;
  float* sdst     = (float*)ws;                          ws += (size_t)N * 4 * 4;
  int*   deg      = (int*)ws;                            ws += (size_t)N * 4;
  int*   rowstart = (int*)ws;                            ws += (size_t)N * 4;
  int*   cursor   = (int*)ws;                            ws += (size_t)N * 4;
  int*   bsum     = (int*)ws;                            ws += 512 * 4;
  int*   eidx     = (int*)ws;                            ws += (size_t)E * 4;
  unsigned short* ph = (unsigned short*)ws;              ws += (size_t)E * 4 * 2;
  int*   flag     = (int*)ws;

  // src32/dst32 scratch aliased into d_out (12.8 MB << 51.2 MB); dead before
  // k_gather overwrites all of d_out.
  int* src32 = (int*)d_out;
  int* dst32 = src32 + E;

  hipMemsetAsync(deg, 0, (size_t)N * 4, stream);

  k_detect<<<1, 64, 0, stream>>>(ei, N, flag);
  k_gemm<<<(N + 63) / 64, 256, 0, stream>>>(x, W, a, hbf, ssrc, sdst, N);
  k_prep<<<(E + 255) / 256, 256, 0, stream>>>(ei, flag, src32, dst32, deg, E);
  k_scan1<<<NB, 256, 0, stream>>>(deg, rowstart, bsum, N);
  k_scan2<<<1, 512, 0, stream>>>(bsum, NB);
  k_scan3<<<NB, 256, 0, stream>>>(rowstart, bsum, cursor, N);
  k_scatter<<<2048, 256, 0, stream>>>(src32, dst32, cursor, eidx, E, N);
  k_attn<<<NB, 256, 0, stream>>>(rowstart, deg, eidx, ssrc, sdst, ph, N);
  k_gather<<<(N + 3) / 4, 256, 0, stream>>>(hbf, rowstart, deg, eidx, ph, out, N);
}

// Round 9
// 276.108 us; speedup vs baseline: 1.3203x; 1.0883x over previous
//
#include <hip/hip_runtime.h>
#include <hip/hip_fp16.h>

using f32x4  = __attribute__((ext_vector_type(4))) float;
using short8 = __attribute__((ext_vector_type(8))) short;
using ushort4_t = __attribute__((ext_vector_type(4))) unsigned short;

#define XP 136  // padded LDS pitch in bf16 elems
#define LOG2E 1.4426950408889634f

static __device__ __forceinline__ unsigned short f2bf(float f) {
  union { float f; unsigned u; } c; c.f = f;
  unsigned u = c.u;
  return (unsigned short)((u + 0x7fffu + ((u >> 16) & 1u)) >> 16);  // RNE
}
static __device__ __forceinline__ float bf2f(unsigned short b) {
  union { unsigned u; float f; } c; c.u = ((unsigned)b) << 16;
  return c.f;
}

// edge_index may arrive as int64 (reference dtype) or int32 (harness downcast).
__global__ __launch_bounds__(64) void k_detect(const void* ei, int nnodes, int* flag) {
  const long long* e64 = (const long long*)ei;
  long long v = e64[threadIdx.x];
  int ok = (v >= 0 && v < (long long)nnodes) ? 1 : 0;
  unsigned long long m = __ballot(ok);
  if (threadIdx.x == 0) *flag = (m == ~0ull) ? 1 : 0;
}

// K1: h = x @ W (bf16 MFMA, f32 accum), h stored bf16.
// Epilogue computes ssrc/sdst[n][4] (PRE-SCALED by log2e) via butterfly reduce.
__global__ __launch_bounds__(256) void k_gemm(const float* __restrict__ x,
                                              const float* __restrict__ W,
                                              const float* __restrict__ a,
                                              unsigned short* __restrict__ hbf,
                                              float* __restrict__ ssrc,
                                              float* __restrict__ sdst, int nnodes) {
  __shared__ __align__(16) unsigned short lx[64 * XP];
  __shared__ __align__(16) unsigned short lw[128 * XP];
  const int tid = threadIdx.x;
  const int n0 = blockIdx.x * 64;

  for (int it = 0; it < 8; ++it) {
    int idx = tid + it * 256;
    int r = idx >> 5, i4 = idx & 31;
    int n = n0 + r;
    float4 v = make_float4(0.f, 0.f, 0.f, 0.f);
    if (n < nnodes) v = *(const float4*)(x + (size_t)n * 128 + i4 * 4);
    ushort4_t b; b.x = f2bf(v.x); b.y = f2bf(v.y); b.z = f2bf(v.z); b.w = f2bf(v.w);
    *(ushort4_t*)&lx[r * XP + i4 * 4] = b;
  }
  for (int it = 0; it < 64; ++it) {
    int idx = tid + it * 256;
    int hh = idx >> 12, i = (idx >> 5) & 127, o = idx & 31;
    int col = hh * 32 + o;
    lw[col * XP + i] = f2bf(W[idx]);
  }
  __syncthreads();

  const int wave = tid >> 6, lane = tid & 63;
  const int m0 = wave * 16;
  const int lr = lane & 15, lh = lane >> 4;

  f32x4 acc[8] = {};
  for (int kk = 0; kk < 4; ++kk) {
    short8 av = *(const short8*)&lx[(m0 + lr) * XP + kk * 32 + lh * 8];
#pragma unroll
    for (int f = 0; f < 8; ++f) {
      short8 bv = *(const short8*)&lw[(f * 16 + lr) * XP + kk * 32 + lh * 8];
      acc[f] = __builtin_amdgcn_mfma_f32_16x16x32_bf16(av, bv, acc[f], 0, 0, 0);
    }
  }

  float avc[4][4];
#pragma unroll
  for (int hh = 0; hh < 4; ++hh) {
    avc[hh][0] = a[hh * 64 + lr];
    avc[hh][1] = a[hh * 64 + 16 + lr];
    avc[hh][2] = a[hh * 64 + 32 + lr];
    avc[hh][3] = a[hh * 64 + 48 + lr];
  }

#pragma unroll
  for (int j = 0; j < 4; ++j) {
    int n = n0 + m0 + lh * 4 + j;
#pragma unroll
    for (int f = 0; f < 8; ++f) {
      if (n < nnodes) hbf[(size_t)n * 128 + f * 16 + lr] = f2bf(acc[f][j]);
    }
#pragma unroll
    for (int hh = 0; hh < 4; ++hh) {
      float s0 = acc[2 * hh][j] * avc[hh][0] + acc[2 * hh + 1][j] * avc[hh][1];
      float s1 = acc[2 * hh][j] * avc[hh][2] + acc[2 * hh + 1][j] * avc[hh][3];
#pragma unroll
      for (int m = 1; m < 16; m <<= 1) {
        s0 += __shfl_xor(s0, m);
        s1 += __shfl_xor(s1, m);
      }
      if (lr == hh && n < nnodes) {
        ssrc[(size_t)n * 4 + hh] = s0 * LOG2E;   // pre-scaled for exp2
        sdst[(size_t)n * 4 + hh] = s1 * LOG2E;
      }
    }
  }
}

// ---- CSR build ----
__global__ __launch_bounds__(256) void k_prep(const void* __restrict__ ei, const int* __restrict__ flag,
                                              int* __restrict__ src32, int* __restrict__ dst32,
                                              int* __restrict__ deg, int E) {
  int e = blockIdx.x * 256 + threadIdx.x;
  if (e >= E) return;
  int is64 = *flag;
  int s, d;
  if (is64) {
    s = (int)((const long long*)ei)[e];
    d = (int)((const long long*)ei)[(size_t)E + e];
  } else {
    s = ((const int*)ei)[e];
    d = ((const int*)ei)[(size_t)E + e];
  }
  src32[e] = s;
  dst32[e] = d;
  atomicAdd(&deg[d], 1);
}

__global__ __launch_bounds__(256) void k_scan1(const int* __restrict__ deg, int* __restrict__ rowstart,
                                               int* __restrict__ bsum, int N) {
  __shared__ int l[256];
  int t = threadIdx.x;
  int gid = blockIdx.x * 256 + t;
  int v = (gid < N) ? deg[gid] : 0;
  l[t] = v;
  __syncthreads();
  for (int off = 1; off < 256; off <<= 1) {
    int u = (t >= off) ? l[t - off] : 0;
    __syncthreads();
    l[t] += u;
    __syncthreads();
  }
  if (gid < N) rowstart[gid] = l[t] - v;
  if (t == 255) bsum[blockIdx.x] = l[255];
}

__global__ __launch_bounds__(512) void k_scan2(int* __restrict__ bsum, int nb) {
  __shared__ int l[512];
  int t = threadIdx.x;
  int v = (t < nb) ? bsum[t] : 0;
  l[t] = v;
  __syncthreads();
  for (int off = 1; off < 512; off <<= 1) {
    int u = (t >= off) ? l[t - off] : 0;
    __syncthreads();
    l[t] += u;
    __syncthreads();
  }
  if (t < nb) bsum[t] = l[t] - v;
}

__global__ __launch_bounds__(256) void k_scan3(int* __restrict__ rowstart, const int* __restrict__ bsum,
                                               int* __restrict__ cursor, int N) {
  int gid = blockIdx.x * 256 + threadIdx.x;
  if (gid < N) {
    int r = rowstart[gid] + bsum[blockIdx.x];
    rowstart[gid] = r;
    cursor[gid] = r;
  }
}

// Partitioned scatter, eidx ONLY (R4-proven: 0.8MB/XCD write window -> no
// write amplification).
__global__ __launch_bounds__(256) void k_scatter(const int* __restrict__ src32,
                                                 const int* __restrict__ dst32,
                                                 int* __restrict__ cursor,
                                                 int* __restrict__ eidx, int E, int N) {
  const int part = blockIdx.x & 7;
  const int wblk = blockIdx.x >> 3;
  const int nwb = gridDim.x >> 3;
  const int lo = (int)(((long long)N * part) >> 3);
  const int hi = (int)(((long long)N * (part + 1)) >> 3);
  for (int e = wblk * 256 + threadIdx.x; e < E; e += nwb * 256) {
    int d = dst32[e];
    if (d >= lo && d < hi) {
      int pos = atomicAdd(&cursor[d], 1);
      eidx[pos] = src32[e];
    }
  }
}

// ---- gather: one wave per dst; bf16 h; p computed once per (edge,head) on
// lanes 0-31 and broadcast via shfl; 8-deep MLP ----
__global__ __launch_bounds__(256) void k_gather(const unsigned short* __restrict__ hbf,
                                                const int* __restrict__ rowstart,
                                                const int* __restrict__ deg,
                                                const int* __restrict__ eidx,
                                                const float* __restrict__ ssrc,
                                                const float* __restrict__ sdst,
                                                float* __restrict__ out, int N) {
  int wid = (blockIdx.x * 256 + threadIdx.x) >> 6;
  int lane = threadIdx.x & 63;
  if (wid >= N) return;
  const int dst = wid;
  const int beg = rowstart[dst];
  const int end = beg + deg[dst];
  const int hh = lane >> 4;              // head of this lane's col pair
  const int lq = lane & 3;               // p-compute: head index
  const int le = lane >> 2;              // p-compute: edge offset within group
  const float sdP = sdst[(size_t)dst * 4 + lq];
  const float sdH = sdst[(size_t)dst * 4 + hh];
  const unsigned* __restrict__ h32 = (const unsigned*)hbf;
  float acc0 = 0.f, acc1 = 0.f, ps = 0.f;

  int i = beg;
  for (; i + 7 < end; i += 8) {
    int s0 = eidx[i + 0], s1 = eidx[i + 1], s2 = eidx[i + 2], s3 = eidx[i + 3];
    int s4 = eidx[i + 4], s5 = eidx[i + 5], s6 = eidx[i + 6], s7 = eidx[i + 7];
    // p for (edge le, head lq) on lanes 0..31 (le<8); clamp for lanes>=32
    int ip = i + le; ip = (ip < end) ? ip : (end - 1);
    int sP = eidx[ip];
    float ev = ssrc[(size_t)sP * 4 + lq] + sdP;
    ev = fmaxf(ev, 0.2f * ev);
    float pv = exp2f(ev);
    unsigned hv0 = h32[((unsigned)s0 << 6) | (unsigned)lane];
    unsigned hv1 = h32[((unsigned)s1 << 6) | (unsigned)lane];
    unsigned hv2 = h32[((unsigned)s2 << 6) | (unsigned)lane];
    unsigned hv3 = h32[((unsigned)s3 << 6) | (unsigned)lane];
    unsigned hv4 = h32[((unsigned)s4 << 6) | (unsigned)lane];
    unsigned hv5 = h32[((unsigned)s5 << 6) | (unsigned)lane];
    unsigned hv6 = h32[((unsigned)s6 << 6) | (unsigned)lane];
    unsigned hv7 = h32[((unsigned)s7 << 6) | (unsigned)lane];
    float p0 = __shfl(pv, (0 << 2) | hh);
    float p1 = __shfl(pv, (1 << 2) | hh);
    float p2 = __shfl(pv, (2 << 2) | hh);
    float p3 = __shfl(pv, (3 << 2) | hh);
    float p4 = __shfl(pv, (4 << 2) | hh);
    float p5 = __shfl(pv, (5 << 2) | hh);
    float p6 = __shfl(pv, (6 << 2) | hh);
    float p7 = __shfl(pv, (7 << 2) | hh);
    acc0 += p0 * bf2f((unsigned short)(hv0 & 0xffff));
    acc1 += p0 * bf2f((unsigned short)(hv0 >> 16));
    acc0 += p1 * bf2f((unsigned short)(hv1 & 0xffff));
    acc1 += p1 * bf2f((unsigned short)(hv1 >> 16));
    acc0 += p2 * bf2f((unsigned short)(hv2 & 0xffff));
    acc1 += p2 * bf2f((unsigned short)(hv2 >> 16));
    acc0 += p3 * bf2f((unsigned short)(hv3 & 0xffff));
    acc1 += p3 * bf2f((unsigned short)(hv3 >> 16));
    acc0 += p4 * bf2f((unsigned short)(hv4 & 0xffff));
    acc1 += p4 * bf2f((unsigned short)(hv4 >> 16));
    acc0 += p5 * bf2f((unsigned short)(hv5 & 0xffff));
    acc1 += p5 * bf2f((unsigned short)(hv5 >> 16));
    acc0 += p6 * bf2f((unsigned short)(hv6 & 0xffff));
    acc1 += p6 * bf2f((unsigned short)(hv6 >> 16));
    acc0 += p7 * bf2f((unsigned short)(hv7 & 0xffff));
    acc1 += p7 * bf2f((unsigned short)(hv7 >> 16));
    ps += ((p0 + p1) + (p2 + p3)) + ((p4 + p5) + (p6 + p7));
  }
  for (; i < end; ++i) {
    int s = eidx[i];
    unsigned hv = h32[((unsigned)s << 6) | (unsigned)lane];
    float ev = ssrc[(size_t)s * 4 + hh] + sdH;
    ev = fmaxf(ev, 0.2f * ev);
    float p = exp2f(ev);
    acc0 += p * bf2f((unsigned short)(hv & 0xffff));
    acc1 += p * bf2f((unsigned short)(hv >> 16));
    ps += p;
  }
  float r = (ps > 0.f) ? 1.f / ps : 0.f;
  __builtin_nontemporal_store(acc0 * r, out + (size_t)dst * 128 + lane * 2);
  __builtin_nontemporal_store(acc1 * r, out + (size_t)dst * 128 + lane * 2 + 1);
}

extern "C" void kernel_launch(void* const* d_in, const int* in_sizes, int n_in,
                              void* d_out, int out_size, void* d_ws, size_t ws_size,
                              hipStream_t stream) {
  const float* x = (const float*)d_in[0];
  const void*  ei = d_in[1];
  const float* W = (const float*)d_in[2];
  const float* a = (const float*)d_in[3];
  float* out = (float*)d_out;

  const int N = in_sizes[0] / 128;
  const int E = in_sizes[1] / 2;
  const int NB = (N + 255) / 256;              // scan blocks (<=512)

  char* ws = (char*)d_ws;
  unsigned short* hbf = (unsigned short*)ws;             ws += (size_t)N * 128 * 2;
  float* ssrc     = (float*)ws;                          ws += (size_t)N * 4 * 4;
  float* sdst     = (float*)ws;                          ws += (size_t)N * 4 * 4;
  int*   deg      = (int*)ws;                            ws += (size_t)N * 4;
  int*   rowstart = (int*)ws;                            ws += (size_t)N * 4;
  int*   cursor   = (int*)ws;                            ws += (size_t)N * 4;
  int*   bsum     = (int*)ws;                            ws += 512 * 4;
  int*   eidx     = (int*)ws;                            ws += (size_t)E * 4;
  int*   flag     = (int*)ws;

  // src32/dst32 scratch aliased into d_out (12.8 MB << 51.2 MB); dead before
  // k_gather overwrites all of d_out.
  int* src32 = (int*)d_out;
  int* dst32 = src32 + E;

  hipMemsetAsync(deg, 0, (size_t)N * 4, stream);

  k_detect<<<1, 64, 0, stream>>>(ei, N, flag);
  k_gemm<<<(N + 63) / 64, 256, 0, stream>>>(x, W, a, hbf, ssrc, sdst, N);
  k_prep<<<(E + 255) / 256, 256, 0, stream>>>(ei, flag, src32, dst32, deg, E);
  k_scan1<<<NB, 256, 0, stream>>>(deg, rowstart, bsum, N);
  k_scan2<<<1, 512, 0, stream>>>(bsum, NB);
  k_scan3<<<NB, 256, 0, stream>>>(rowstart, bsum, cursor, N);
  k_scatter<<<2048, 256, 0, stream>>>(src32, dst32, cursor, eidx, E, N);
  k_gather<<<(N + 3) / 4, 256, 0, stream>>>(hbf, rowstart, deg, eidx, ssrc, sdst, out, N);
}